// Round 4
// baseline (220.931 us; speedup 1.0000x reference)
//
#include <hip/hip_runtime.h>
#include <hip/hip_bf16.h>

#define VNUM 6890
#define KJ 24
#define NBETA 10
#define NPOSE 207
#define KPAD 224        // NPOSE padded to 7*32; cols 207..216 carry betas/sd
#define BATCH 1024
#define N3 20670        // VNUM*3
#define N3PAD 20672     // 323*64
#define VPAD 6912       // 432*16

// d_out element offsets (f32 elements)
#define OUT_V  0
#define OUT_JT 21166080
#define OUT_J  21239808
#define OUT_RM 21313536

// ws offsets (float units)
#define WS_JVJS 0                 // 792 floats
#define WS_ABF  792               // ushort[1024*480]  = 245760 f -> ends 246552
#define WS_WBF  246552            // ushort[6912*40]   = 138240 f -> ends 384792
#define WS_PFB  384792            // ushort[1024*224]  = 114688 f -> ends 499480
#define WS_PDT  499480            // ushort[20672*224] = 2315264 f -> ends 2814744

typedef unsigned short ushort;
typedef __attribute__((ext_vector_type(8))) short short8v;
typedef __attribute__((ext_vector_type(4))) float floatx4;

__device__ __forceinline__ ushort f2bfu(float x) {
  __hip_bfloat16 h = __float2bfloat16(x);
  union { __hip_bfloat16 h; ushort u; } cv; cv.h = h; return cv.u;
}

// ---------------------------------------------------------------------------
// Kernel 0: JvJs accumulation, split over 4 V-chunks, atomicAdd combine.
// ---------------------------------------------------------------------------
__global__ __launch_bounds__(256) void jreg_kernel(
    const float* __restrict__ Jr, const float* __restrict__ vt,
    const float* __restrict__ sd, float* __restrict__ JvJs) {
  const int j = blockIdx.x;
  const int chunk = blockIdx.y;
  const int t = threadIdx.x;
  const int lane = t & 63, wid = t >> 6;
  const int vbeg = chunk * 1723;
  const int vend = (vbeg + 1723 < VNUM) ? vbeg + 1723 : VNUM;
  __shared__ float red[4][33];
  float acc[33];
#pragma unroll
  for (int q = 0; q < 33; q++) acc[q] = 0.0f;
  for (int v = vbeg + t; v < vend; v += 256) {
    float r = Jr[j * VNUM + v];
    const float* vtp = vt + v * 3;
    const float* sdp = sd + v * 30;
    acc[0] += r * vtp[0];
    acc[1] += r * vtp[1];
    acc[2] += r * vtp[2];
#pragma unroll
    for (int q = 0; q < 30; q++) acc[3 + q] += r * sdp[q];
  }
#pragma unroll
  for (int q = 0; q < 33; q++) {
    float x = acc[q];
    for (int off = 32; off > 0; off >>= 1) x += __shfl_down(x, off, 64);
    if (lane == 0) red[wid][q] = x;
  }
  __syncthreads();
  if (t < 33)
    atomicAdd(&JvJs[j * 33 + t], red[0][t] + red[1][t] + red[2][t] + red[3][t]);
}

// ---------------------------------------------------------------------------
// Kernel 1: per-batch: rodrigues, joints_t, pose_feature+betas (bf16), chain,
// A written directly as bf16 in MFMA layout: Abf[b][n(12)][k(40)], k>=24 zero.
// pfb row layout: [0..206]=pose_feature, [207..216]=betas, [217..223]=0.
// ---------------------------------------------------------------------------
__global__ __launch_bounds__(64) void batch_prep(
    const float* __restrict__ body_pose, const float* __restrict__ betas,
    const float* __restrict__ global_orient, const float* __restrict__ JvJs,
    float* __restrict__ out_jt, float* __restrict__ out_j, float* __restrict__ out_rm,
    ushort* __restrict__ pfb, ushort* __restrict__ Abf) {
  const int b = blockIdx.x;
  const int t = threadIdx.x;
  __shared__ float R[24][9];
  __shared__ float jt[24][3];
  __shared__ float chR[24][9];
  __shared__ float cht[24][3];

  if (t < 24) {
    float ax, ay, az;
    if (t == 0) {
      ax = global_orient[b * 3 + 0];
      ay = global_orient[b * 3 + 1];
      az = global_orient[b * 3 + 2];
    } else {
      const float* p = body_pose + (size_t)b * 69 + (t - 1) * 3;
      ax = p[0]; ay = p[1]; az = p[2];
    }
    float px = ax + 1e-8f, py = ay + 1e-8f, pz = az + 1e-8f;
    float angle = sqrtf(px * px + py * py + pz * pz);
    float inv = 1.0f / angle;
    float rx = ax * inv, ry = ay * inv, rz = az * inv;
    float s = sinf(angle), c = cosf(angle);
    float cc = 1.0f - c;
    float m[9];
    m[0] = 1.0f - cc * (ry * ry + rz * rz);
    m[1] = -s * rz + cc * rx * ry;
    m[2] =  s * ry + cc * rx * rz;
    m[3] =  s * rz + cc * rx * ry;
    m[4] = 1.0f - cc * (rx * rx + rz * rz);
    m[5] = -s * rx + cc * ry * rz;
    m[6] = -s * ry + cc * rx * rz;
    m[7] =  s * rx + cc * ry * rz;
    m[8] = 1.0f - cc * (rx * rx + ry * ry);
#pragma unroll
    for (int e = 0; e < 9; e++) {
      R[t][e] = m[e];
      out_rm[(size_t)b * 216 + t * 9 + e] = m[e];
    }
  }
  for (int idx = t; idx < 72; idx += 64) {
    int j = idx / 3, c = idx % 3;
    const float* JJ = JvJs + j * 33;
    float s = JJ[c];
    const float* be = betas + (size_t)b * NBETA;
#pragma unroll
    for (int l = 0; l < NBETA; l++) s += be[l] * JJ[3 + c * 10 + l];
    jt[j][c] = s;
    out_jt[(size_t)b * 72 + idx] = s;
  }
  __syncthreads();
  for (int mI = t; mI < KPAD; mI += 64) {
    float val = 0.0f;
    if (mI < NPOSE) {
      int k = 1 + mI / 9, e = mI % 9;
      val = R[k][e] - ((e == 0 || e == 4 || e == 8) ? 1.0f : 0.0f);
    } else if (mI < NPOSE + NBETA) {
      val = betas[(size_t)b * NBETA + (mI - NPOSE)];
    }
    pfb[(size_t)b * KPAD + mI] = f2bfu(val);
  }
  if (t == 0) {
    const int par[24] = {-1, 0, 0, 0, 1, 2, 3, 4, 5, 6, 7, 8, 9, 9, 9, 12, 13, 14, 16, 17, 18, 19, 20, 21};
#pragma unroll
    for (int e = 0; e < 9; e++) chR[0][e] = R[0][e];
    cht[0][0] = jt[0][0]; cht[0][1] = jt[0][1]; cht[0][2] = jt[0][2];
    for (int k = 1; k < 24; k++) {
      int p = par[k];
      float rel0 = jt[k][0] - jt[p][0];
      float rel1 = jt[k][1] - jt[p][1];
      float rel2 = jt[k][2] - jt[p][2];
#pragma unroll
      for (int i = 0; i < 3; i++) {
        float a0 = chR[p][i * 3 + 0], a1 = chR[p][i * 3 + 1], a2 = chR[p][i * 3 + 2];
        chR[k][i * 3 + 0] = a0 * R[k][0] + a1 * R[k][3] + a2 * R[k][6];
        chR[k][i * 3 + 1] = a0 * R[k][1] + a1 * R[k][4] + a2 * R[k][7];
        chR[k][i * 3 + 2] = a0 * R[k][2] + a1 * R[k][5] + a2 * R[k][8];
        cht[k][i] = a0 * rel0 + a1 * rel1 + a2 * rel2 + cht[p][i];
      }
    }
  }
  __syncthreads();
  if (t < 24) {
    int k = t;
#pragma unroll
    for (int i = 0; i < 3; i++) out_j[(size_t)b * 72 + k * 3 + i] = cht[k][i];
  }
  // A in bf16, layout: Abf[b*480 + n*40 + k], n = i*4+j
  for (int e = t; e < 480; e += 64) {
    int n = e / 40, k = e - (e / 40) * 40;
    float val = 0.0f;
    if (k < 24) {
      int i = n >> 2, jj = n & 3;
      if (jj < 3) {
        val = chR[k][i * 3 + jj];
      } else {
        val = cht[k][i] - (chR[k][i * 3 + 0] * jt[k][0] +
                           chR[k][i * 3 + 1] * jt[k][1] +
                           chR[k][i * 3 + 2] * jt[k][2]);
      }
    }
    Abf[(size_t)b * 480 + e] = f2bfu(val);
  }
}

// ---------------------------------------------------------------------------
// Kernel 2: pdT[n][k] = bf16(pd[k][n]) for k<207; k in 207..216 = sd[n][k-207];
// k>=217 zero. 1080 of the 2261 blocks also convert lbs_weights -> bf16 [VPAD][40].
// ---------------------------------------------------------------------------
__global__ __launch_bounds__(256) void transpose_pd(
    const float* __restrict__ pd, ushort* __restrict__ pdT,
    const float* __restrict__ sd,
    const float* __restrict__ w, ushort* __restrict__ wbf) {
  {
    int lb = blockIdx.y * 323 + blockIdx.x;
    if (lb < 1080) {
      int i = lb * 256 + threadIdx.x;          // < 6912*40 = 276480 exactly
      int v = i / 40, k = i - v * 40;
      float x = (v < VNUM && k < 24) ? w[v * 24 + k] : 0.0f;
      wbf[i] = f2bfu(x);
    }
  }
  __shared__ float tile[32][65];
  const int t = threadIdx.x;
  const int n0 = blockIdx.x * 64;
  const int k0 = blockIdx.y * 32;
  const int c = t & 63;
  for (int r = t >> 6; r < 32; r += 4) {
    int k = k0 + r, n = n0 + c;
    float x = 0.0f;
    if (n < N3) {
      if (k < NPOSE) x = pd[(size_t)k * N3 + n];
      else if (k < NPOSE + NBETA) x = sd[(size_t)n * 10 + (k - NPOSE)];
    }
    tile[r][c] = x;
  }
  __syncthreads();
  const int n = t >> 2;
  const int j0 = (t & 3) * 8;
  unsigned int outw[4];
#pragma unroll
  for (int jj = 0; jj < 4; jj++) {
    unsigned int lo = f2bfu(tile[j0 + jj * 2][n]);
    unsigned int hi = f2bfu(tile[j0 + jj * 2 + 1][n]);
    outw[jj] = lo | (hi << 16);
  }
  *(uint4*)&pdT[(size_t)(n0 + n) * KPAD + k0 + j0] =
      make_uint4(outw[0], outw[1], outw[2], outw[3]);
}

// ---------------------------------------------------------------------------
// Kernel 3 (fused): per block = 64 batches x 16 vertices.
// Phase 1 (vposed): 64x48 tile = pf_ext @ pdT_ext + vt via MFMA -> LDS vpS.
//   vpS rows are wave-private (wave wv computes batches wv*16..+15).
// Phase 2 (blend): per wave, 16 iterations over its own batches:
//   T^T = mfma(Abf_frag, wf) -> lane(quad<3,l15) holds row quad of T[v=l15];
//   p from vpS (LDS), out_v written exactly once. No vposed HBM round-trip.
// LDS: Bs 21.5K + vpS 12.8K + vtS -> ~34.5 KB -> 4 blocks/CU.
// ---------------------------------------------------------------------------
__global__ __launch_bounds__(256, 4) void fused_mfma(
    const ushort* __restrict__ pfb, const ushort* __restrict__ pdT,
    const float* __restrict__ vt, const ushort* __restrict__ wbf,
    const ushort* __restrict__ Abf, float* __restrict__ out_v) {
  __shared__ __align__(16) ushort Bs[48 * KPAD];   // 21504 B
  __shared__ float vpS[64 * 50];                   // 12800 B, stride 50
  __shared__ float vtS[48];
  const int tid = threadIdx.x;
  const int lane = tid & 63, wv = tid >> 6;
  const int l15 = lane & 15, quad = lane >> 4;
  const int v0 = blockIdx.x * 16;          // vertex group
  const int bm = blockIdx.y * 64;          // batch tile

  // W fragment for this block's 16 vertices (same for all waves, L1/L2 hot)
  const short8v wf = *(const short8v*)(wbf + (size_t)(v0 + l15) * 40 + quad * 8);

  // Phase-1 A-fragments direct from global (pfb L2-resident, 431x reuse)
  short8v av[7];
  const ushort* arow = pfb + (size_t)(bm + wv * 16 + l15) * KPAD;
#pragma unroll
  for (int kb = 0; kb < 7; kb++)
    av[kb] = *(const short8v*)(arow + kb * 32 + quad * 8);

  // Stage pdT rows v0*3 .. v0*3+47 (clamped) into LDS
  {
    const uint4* src = (const uint4*)pdT;
    uint4* dB = (uint4*)Bs;
    for (int e = tid; e < 48 * 28; e += 256) {
      int row = e / 28, q = e - row * 28;
      int n = v0 * 3 + row;
      if (n >= N3PAD) n = 0;               // garbage rows feed inactive lanes only
      dB[row * 28 + q] = src[(size_t)n * 28 + q];
    }
    if (tid < 48) {
      int gn = v0 * 3 + tid;
      vtS[tid] = (gn < N3) ? vt[gn] : 0.0f;
    }
  }
  __syncthreads();

  // Phase 1: 64x48 vposed tile
  floatx4 acc[3];
  const floatx4 zero = {0.0f, 0.0f, 0.0f, 0.0f};
#pragma unroll
  for (int ns = 0; ns < 3; ns++) acc[ns] = zero;
#pragma unroll
  for (int kb = 0; kb < 7; kb++) {
#pragma unroll
    for (int ns = 0; ns < 3; ns++) {
      short8v bv = *(const short8v*)&Bs[(ns * 16 + l15) * KPAD + kb * 32 + quad * 8];
      acc[ns] = __builtin_amdgcn_mfma_f32_16x16x32_bf16(av[kb], bv, acc[ns], 0, 0, 0);
    }
  }
#pragma unroll
  for (int ns = 0; ns < 3; ns++) {
    int col = ns * 16 + l15;
    float vtv = vtS[col];
#pragma unroll
    for (int r = 0; r < 4; r++)
      vpS[(wv * 16 + quad * 4 + r) * 50 + col] = acc[ns][r] + vtv;
  }
  // Wave-private handoff: wave's own ds_writes complete before its reads.
  __builtin_amdgcn_sched_barrier(0);
  __builtin_amdgcn_s_waitcnt(0xc07f);   // lgkmcnt(0)
  __builtin_amdgcn_sched_barrier(0);

  // Phase 2: blend, wave wv handles batches bm + wv*16 .. +15
  const int gv = v0 + l15;
  const bool active = (quad < 3) && (gv < VNUM);
  const size_t vbase = (size_t)gv * 3;

#pragma unroll
  for (int i = 0; i < 16; i++) {
    const int b = wv * 16 + i;
    const size_t gb = (size_t)(bm + b);
    short8v afrag = *(const short8v*)(Abf + gb * 480 + l15 * 40 + quad * 8);
    floatx4 t = zero;
    t = __builtin_amdgcn_mfma_f32_16x16x32_bf16(afrag, wf, t, 0, 0, 0);
    float px = vpS[b * 50 + 3 * l15 + 0];
    float py = vpS[b * 50 + 3 * l15 + 1];
    float pz = vpS[b * 50 + 3 * l15 + 2];
    if (active) {
      out_v[gb * N3 + vbase + quad] = t[0] * px + t[1] * py + t[2] * pz + t[3];
    }
  }
}

extern "C" void kernel_launch(void* const* d_in, const int* in_sizes, int n_in,
                              void* d_out, int out_size, void* d_ws, size_t ws_size,
                              hipStream_t stream) {
  const float* body_pose     = (const float*)d_in[0];
  const float* betas         = (const float*)d_in[1];
  const float* global_orient = (const float*)d_in[2];
  const float* v_template    = (const float*)d_in[3];
  const float* shapedirs     = (const float*)d_in[4];
  const float* posedirs      = (const float*)d_in[5];
  const float* J_regressor   = (const float*)d_in[6];
  const float* lbs_weights   = (const float*)d_in[7];

  float* out = (float*)d_out;
  float* out_v  = out + OUT_V;
  float* out_jt = out + OUT_JT;
  float* out_j  = out + OUT_J;
  float* out_rm = out + OUT_RM;

  float* ws = (float*)d_ws;
  float* JvJs = ws + WS_JVJS;
  ushort* Abf = (ushort*)(ws + WS_ABF);
  ushort* wbf = (ushort*)(ws + WS_WBF);
  ushort* pfb = (ushort*)(ws + WS_PFB);
  ushort* pdT = (ushort*)(ws + WS_PDT);

  hipMemsetAsync(JvJs, 0, KJ * 33 * sizeof(float), stream);
  jreg_kernel<<<dim3(KJ, 4), 256, 0, stream>>>(J_regressor, v_template, shapedirs, JvJs);
  transpose_pd<<<dim3(323, 7), 256, 0, stream>>>(posedirs, pdT, shapedirs,
                                                 lbs_weights, wbf);
  batch_prep<<<BATCH, 64, 0, stream>>>(body_pose, betas, global_orient, JvJs,
                                       out_jt, out_j, out_rm, pfb, Abf);
  fused_mfma<<<dim3(431, 16), 256, 0, stream>>>(pfb, pdT, v_template, wbf,
                                                Abf, out_v);
}

// Round 5
// 201.908 us; speedup vs baseline: 1.0942x; 1.0942x over previous
//
#include <hip/hip_runtime.h>
#include <hip/hip_bf16.h>

#define VNUM 6890
#define KJ 24
#define NBETA 10
#define NPOSE 207
#define KPAD 224        // NPOSE padded to 7*32; cols 207..216 carry betas/sd
#define BATCH 1024
#define N3 20670        // VNUM*3
#define N3PAD 20672     // 323*64
#define VPAD 6912       // 432*16

// d_out element offsets (f32 elements)
#define OUT_V  0
#define OUT_JT 21166080
#define OUT_J  21239808
#define OUT_RM 21313536

// ws offsets (float units)
#define WS_JVJS 0                 // 792 floats
#define WS_ABF  792               // ushort[1024*480]  = 245760 f -> ends 246552
#define WS_WBF  246552            // ushort[6912*40]   = 138240 f -> ends 384792
#define WS_PFB  384792            // ushort[1024*224]  = 114688 f -> ends 499480
#define WS_PDT  499480            // ushort[20672*224] = 2315264 f -> ends 2814744

typedef unsigned short ushort;
typedef __attribute__((ext_vector_type(8))) short short8v;
typedef __attribute__((ext_vector_type(4))) float floatx4;

__device__ __forceinline__ ushort f2bfu(float x) {
  __hip_bfloat16 h = __float2bfloat16(x);
  union { __hip_bfloat16 h; ushort u; } cv; cv.h = h; return cv.u;
}

// ---------------------------------------------------------------------------
// Kernel 0: JvJs accumulation, split over 4 V-chunks, atomicAdd combine.
// ---------------------------------------------------------------------------
__global__ __launch_bounds__(256) void jreg_kernel(
    const float* __restrict__ Jr, const float* __restrict__ vt,
    const float* __restrict__ sd, float* __restrict__ JvJs) {
  const int j = blockIdx.x;
  const int chunk = blockIdx.y;
  const int t = threadIdx.x;
  const int lane = t & 63, wid = t >> 6;
  const int vbeg = chunk * 1723;
  const int vend = (vbeg + 1723 < VNUM) ? vbeg + 1723 : VNUM;
  __shared__ float red[4][33];
  float acc[33];
#pragma unroll
  for (int q = 0; q < 33; q++) acc[q] = 0.0f;
  for (int v = vbeg + t; v < vend; v += 256) {
    float r = Jr[j * VNUM + v];
    const float* vtp = vt + v * 3;
    const float* sdp = sd + v * 30;
    acc[0] += r * vtp[0];
    acc[1] += r * vtp[1];
    acc[2] += r * vtp[2];
#pragma unroll
    for (int q = 0; q < 30; q++) acc[3 + q] += r * sdp[q];
  }
#pragma unroll
  for (int q = 0; q < 33; q++) {
    float x = acc[q];
    for (int off = 32; off > 0; off >>= 1) x += __shfl_down(x, off, 64);
    if (lane == 0) red[wid][q] = x;
  }
  __syncthreads();
  if (t < 33)
    atomicAdd(&JvJs[j * 33 + t], red[0][t] + red[1][t] + red[2][t] + red[3][t]);
}

// ---------------------------------------------------------------------------
// Kernel 1: per-batch: rodrigues, joints_t, pose_feature+betas (bf16), chain,
// A written directly as bf16 in MFMA layout: Abf[b][n(12)][k(40)], k>=24 zero.
// pfb row layout: [0..206]=pose_feature, [207..216]=betas, [217..223]=0.
// ---------------------------------------------------------------------------
__global__ __launch_bounds__(64) void batch_prep(
    const float* __restrict__ body_pose, const float* __restrict__ betas,
    const float* __restrict__ global_orient, const float* __restrict__ JvJs,
    float* __restrict__ out_jt, float* __restrict__ out_j, float* __restrict__ out_rm,
    ushort* __restrict__ pfb, ushort* __restrict__ Abf) {
  const int b = blockIdx.x;
  const int t = threadIdx.x;
  __shared__ float R[24][9];
  __shared__ float jt[24][3];
  __shared__ float chR[24][9];
  __shared__ float cht[24][3];

  if (t < 24) {
    float ax, ay, az;
    if (t == 0) {
      ax = global_orient[b * 3 + 0];
      ay = global_orient[b * 3 + 1];
      az = global_orient[b * 3 + 2];
    } else {
      const float* p = body_pose + (size_t)b * 69 + (t - 1) * 3;
      ax = p[0]; ay = p[1]; az = p[2];
    }
    float px = ax + 1e-8f, py = ay + 1e-8f, pz = az + 1e-8f;
    float angle = sqrtf(px * px + py * py + pz * pz);
    float inv = 1.0f / angle;
    float rx = ax * inv, ry = ay * inv, rz = az * inv;
    float s = sinf(angle), c = cosf(angle);
    float cc = 1.0f - c;
    float m[9];
    m[0] = 1.0f - cc * (ry * ry + rz * rz);
    m[1] = -s * rz + cc * rx * ry;
    m[2] =  s * ry + cc * rx * rz;
    m[3] =  s * rz + cc * rx * ry;
    m[4] = 1.0f - cc * (rx * rx + rz * rz);
    m[5] = -s * rx + cc * ry * rz;
    m[6] = -s * ry + cc * rx * rz;
    m[7] =  s * rx + cc * ry * rz;
    m[8] = 1.0f - cc * (rx * rx + ry * ry);
#pragma unroll
    for (int e = 0; e < 9; e++) {
      R[t][e] = m[e];
      out_rm[(size_t)b * 216 + t * 9 + e] = m[e];
    }
  }
  for (int idx = t; idx < 72; idx += 64) {
    int j = idx / 3, c = idx % 3;
    const float* JJ = JvJs + j * 33;
    float s = JJ[c];
    const float* be = betas + (size_t)b * NBETA;
#pragma unroll
    for (int l = 0; l < NBETA; l++) s += be[l] * JJ[3 + c * 10 + l];
    jt[j][c] = s;
    out_jt[(size_t)b * 72 + idx] = s;
  }
  __syncthreads();
  for (int mI = t; mI < KPAD; mI += 64) {
    float val = 0.0f;
    if (mI < NPOSE) {
      int k = 1 + mI / 9, e = mI % 9;
      val = R[k][e] - ((e == 0 || e == 4 || e == 8) ? 1.0f : 0.0f);
    } else if (mI < NPOSE + NBETA) {
      val = betas[(size_t)b * NBETA + (mI - NPOSE)];
    }
    pfb[(size_t)b * KPAD + mI] = f2bfu(val);
  }
  if (t == 0) {
    const int par[24] = {-1, 0, 0, 0, 1, 2, 3, 4, 5, 6, 7, 8, 9, 9, 9, 12, 13, 14, 16, 17, 18, 19, 20, 21};
#pragma unroll
    for (int e = 0; e < 9; e++) chR[0][e] = R[0][e];
    cht[0][0] = jt[0][0]; cht[0][1] = jt[0][1]; cht[0][2] = jt[0][2];
    for (int k = 1; k < 24; k++) {
      int p = par[k];
      float rel0 = jt[k][0] - jt[p][0];
      float rel1 = jt[k][1] - jt[p][1];
      float rel2 = jt[k][2] - jt[p][2];
#pragma unroll
      for (int i = 0; i < 3; i++) {
        float a0 = chR[p][i * 3 + 0], a1 = chR[p][i * 3 + 1], a2 = chR[p][i * 3 + 2];
        chR[k][i * 3 + 0] = a0 * R[k][0] + a1 * R[k][3] + a2 * R[k][6];
        chR[k][i * 3 + 1] = a0 * R[k][1] + a1 * R[k][4] + a2 * R[k][7];
        chR[k][i * 3 + 2] = a0 * R[k][2] + a1 * R[k][5] + a2 * R[k][8];
        cht[k][i] = a0 * rel0 + a1 * rel1 + a2 * rel2 + cht[p][i];
      }
    }
  }
  __syncthreads();
  if (t < 24) {
    int k = t;
#pragma unroll
    for (int i = 0; i < 3; i++) out_j[(size_t)b * 72 + k * 3 + i] = cht[k][i];
  }
  // A in bf16, layout: Abf[b*480 + n*40 + k], n = i*4+j
  for (int e = t; e < 480; e += 64) {
    int n = e / 40, k = e - (e / 40) * 40;
    float val = 0.0f;
    if (k < 24) {
      int i = n >> 2, jj = n & 3;
      if (jj < 3) {
        val = chR[k][i * 3 + jj];
      } else {
        val = cht[k][i] - (chR[k][i * 3 + 0] * jt[k][0] +
                           chR[k][i * 3 + 1] * jt[k][1] +
                           chR[k][i * 3 + 2] * jt[k][2]);
      }
    }
    Abf[(size_t)b * 480 + e] = f2bfu(val);
  }
}

// ---------------------------------------------------------------------------
// Kernel 2: pdT[n][k] = bf16(pd[k][n]) for k<207; k in 207..216 = sd[n][k-207];
// k>=217 zero. 1080 of the 2261 blocks also convert lbs_weights -> bf16 [VPAD][40].
// ---------------------------------------------------------------------------
__global__ __launch_bounds__(256) void transpose_pd(
    const float* __restrict__ pd, ushort* __restrict__ pdT,
    const float* __restrict__ sd,
    const float* __restrict__ w, ushort* __restrict__ wbf) {
  {
    int lb = blockIdx.y * 323 + blockIdx.x;
    if (lb < 1080) {
      int i = lb * 256 + threadIdx.x;          // < 6912*40 = 276480 exactly
      int v = i / 40, k = i - v * 40;
      float x = (v < VNUM && k < 24) ? w[v * 24 + k] : 0.0f;
      wbf[i] = f2bfu(x);
    }
  }
  __shared__ float tile[32][65];
  const int t = threadIdx.x;
  const int n0 = blockIdx.x * 64;
  const int k0 = blockIdx.y * 32;
  const int c = t & 63;
  for (int r = t >> 6; r < 32; r += 4) {
    int k = k0 + r, n = n0 + c;
    float x = 0.0f;
    if (n < N3) {
      if (k < NPOSE) x = pd[(size_t)k * N3 + n];
      else if (k < NPOSE + NBETA) x = sd[(size_t)n * 10 + (k - NPOSE)];
    }
    tile[r][c] = x;
  }
  __syncthreads();
  const int n = t >> 2;
  const int j0 = (t & 3) * 8;
  unsigned int outw[4];
#pragma unroll
  for (int jj = 0; jj < 4; jj++) {
    unsigned int lo = f2bfu(tile[j0 + jj * 2][n]);
    unsigned int hi = f2bfu(tile[j0 + jj * 2 + 1][n]);
    outw[jj] = lo | (hi << 16);
  }
  *(uint4*)&pdT[(size_t)(n0 + n) * KPAD + k0 + j0] =
      make_uint4(outw[0], outw[1], outw[2], outw[3]);
}

// ---------------------------------------------------------------------------
// Kernel 3 (fused, v2): per block = 64 batches x 16 vertices.
// Grid = (x:16 batch-tiles FASTEST, y:431 vertex-groups) -> the 16 blocks
// sharing one pdT tile are consecutive block ids (L2/L3-hot), per-yg working
// set small; pfb/Abf are L2-resident sweeps. (R4 had this transposed ->
// 16 cold re-fetches of every pdT tile, FETCH 83.6 MB, latency-bound.)
// Phase 1 (vposed): 64x48 tile = pf_ext @ pdT_ext + vt via MFMA -> LDS vpS
//   (rows wave-private).
// Phase 2 (blend): per wave, its own 16 batches; afrag prefetched 4-deep
//   (static ring, full unroll) so global-load latency hides under MFMA+store.
// ---------------------------------------------------------------------------
__global__ __launch_bounds__(256, 4) void fused_mfma(
    const ushort* __restrict__ pfb, const ushort* __restrict__ pdT,
    const float* __restrict__ vt, const ushort* __restrict__ wbf,
    const ushort* __restrict__ Abf, float* __restrict__ out_v) {
  __shared__ __align__(16) ushort Bs[48 * KPAD];   // 21504 B
  __shared__ float vpS[64 * 50];                   // 12800 B, stride 50
  __shared__ float vtS[48];
  const int tid = threadIdx.x;
  const int lane = tid & 63, wv = tid >> 6;
  const int l15 = lane & 15, quad = lane >> 4;
  const int bm = blockIdx.x * 64;          // batch tile (fastest)
  const int v0 = blockIdx.y * 16;          // vertex group

  // W fragment for this block's 16 vertices (same for all waves, L1/L2 hot)
  const short8v wf = *(const short8v*)(wbf + (size_t)(v0 + l15) * 40 + quad * 8);

  // Phase-1 A-fragments direct from global (pfb L2-resident)
  short8v av[7];
  const ushort* arow = pfb + (size_t)(bm + wv * 16 + l15) * KPAD;
#pragma unroll
  for (int kb = 0; kb < 7; kb++)
    av[kb] = *(const short8v*)(arow + kb * 32 + quad * 8);

  // Stage pdT rows v0*3 .. v0*3+47 (clamped) into LDS
  {
    const uint4* src = (const uint4*)pdT;
    uint4* dB = (uint4*)Bs;
    for (int e = tid; e < 48 * 28; e += 256) {
      int row = e / 28, q = e - row * 28;
      int n = v0 * 3 + row;
      if (n >= N3PAD) n = 0;               // garbage rows feed inactive lanes only
      dB[row * 28 + q] = src[(size_t)n * 28 + q];
    }
    if (tid < 48) {
      int gn = v0 * 3 + tid;
      vtS[tid] = (gn < N3) ? vt[gn] : 0.0f;
    }
  }
  __syncthreads();

  // Phase 1: 64x48 vposed tile
  floatx4 acc[3];
  const floatx4 zero = {0.0f, 0.0f, 0.0f, 0.0f};
#pragma unroll
  for (int ns = 0; ns < 3; ns++) acc[ns] = zero;
#pragma unroll
  for (int kb = 0; kb < 7; kb++) {
#pragma unroll
    for (int ns = 0; ns < 3; ns++) {
      short8v bv = *(const short8v*)&Bs[(ns * 16 + l15) * KPAD + kb * 32 + quad * 8];
      acc[ns] = __builtin_amdgcn_mfma_f32_16x16x32_bf16(av[kb], bv, acc[ns], 0, 0, 0);
    }
  }
#pragma unroll
  for (int ns = 0; ns < 3; ns++) {
    int col = ns * 16 + l15;
    float vtv = vtS[col];
#pragma unroll
    for (int r = 0; r < 4; r++)
      vpS[(wv * 16 + quad * 4 + r) * 50 + col] = acc[ns][r] + vtv;
  }
  // Wave-private handoff: wave's own ds_writes complete before its reads.
  __builtin_amdgcn_sched_barrier(0);
  __builtin_amdgcn_s_waitcnt(0xc07f);   // lgkmcnt(0)
  __builtin_amdgcn_sched_barrier(0);

  // Phase 2: blend, wave wv handles batches bm + wv*16 .. +15
  const int gv = v0 + l15;
  const bool active = (quad < 3) && (gv < VNUM);
  const size_t vbase = (size_t)gv * 3;
  const ushort* abase = Abf + (size_t)(bm + wv * 16) * 480 + l15 * 40 + quad * 8;

  // 4-deep prefetch ring (static indices via full unroll)
  short8v apre[4];
#pragma unroll
  for (int i = 0; i < 4; i++) apre[i] = *(const short8v*)(abase + i * 480);

#pragma unroll
  for (int i = 0; i < 16; i++) {
    const int b = wv * 16 + i;
    const size_t gb = (size_t)(bm + b);
    short8v afrag = apre[i & 3];
    if (i < 12) apre[i & 3] = *(const short8v*)(abase + (i + 4) * 480);
    floatx4 t = zero;
    t = __builtin_amdgcn_mfma_f32_16x16x32_bf16(afrag, wf, t, 0, 0, 0);
    float px = vpS[b * 50 + 3 * l15 + 0];
    float py = vpS[b * 50 + 3 * l15 + 1];
    float pz = vpS[b * 50 + 3 * l15 + 2];
    if (active) {
      out_v[gb * N3 + vbase + quad] = t[0] * px + t[1] * py + t[2] * pz + t[3];
    }
  }
}

extern "C" void kernel_launch(void* const* d_in, const int* in_sizes, int n_in,
                              void* d_out, int out_size, void* d_ws, size_t ws_size,
                              hipStream_t stream) {
  const float* body_pose     = (const float*)d_in[0];
  const float* betas         = (const float*)d_in[1];
  const float* global_orient = (const float*)d_in[2];
  const float* v_template    = (const float*)d_in[3];
  const float* shapedirs     = (const float*)d_in[4];
  const float* posedirs      = (const float*)d_in[5];
  const float* J_regressor   = (const float*)d_in[6];
  const float* lbs_weights   = (const float*)d_in[7];

  float* out = (float*)d_out;
  float* out_v  = out + OUT_V;
  float* out_jt = out + OUT_JT;
  float* out_j  = out + OUT_J;
  float* out_rm = out + OUT_RM;

  float* ws = (float*)d_ws;
  float* JvJs = ws + WS_JVJS;
  ushort* Abf = (ushort*)(ws + WS_ABF);
  ushort* wbf = (ushort*)(ws + WS_WBF);
  ushort* pfb = (ushort*)(ws + WS_PFB);
  ushort* pdT = (ushort*)(ws + WS_PDT);

  hipMemsetAsync(JvJs, 0, KJ * 33 * sizeof(float), stream);
  jreg_kernel<<<dim3(KJ, 4), 256, 0, stream>>>(J_regressor, v_template, shapedirs, JvJs);
  transpose_pd<<<dim3(323, 7), 256, 0, stream>>>(posedirs, pdT, shapedirs,
                                                 lbs_weights, wbf);
  batch_prep<<<BATCH, 64, 0, stream>>>(body_pose, betas, global_orient, JvJs,
                                       out_jt, out_j, out_rm, pfb, Abf);
  fused_mfma<<<dim3(16, 431), 256, 0, stream>>>(pfb, pdT, v_template, wbf,
                                                Abf, out_v);
}